// Round 1
// baseline (308.033 us; speedup 1.0000x reference)
//
#include <hip/hip_runtime.h>
#include <hip/hip_cooperative_groups.h>
#include <math.h>

namespace cg = cooperative_groups;

// p = (||c2[:,:,7,7]-vmask1|| + ||c3[:,:,3,3]-vmask2||) / 38400
// m = exact lower median (k-th smallest, k=(n-1)/2) of each gathered slice
// q = (||(tm1<m1?0:1)-amask1|| + ||(tm2<m2?0:1)-amask2||) / 384
//
// R4: single cooperative kernel. Harness fills (2x93us @86% HBM peak) +
// input restores ~= 262us of the 283.6us are fixed; our ~20us was 3 dispatches
// + a W1/W2 round-trip. Fuse: zero-in-kernel, gather values held in REGISTERS
// across grid.sync() (no W arrays at all), every block redundantly rescans the
// 16KB histogram to learn the median bin (avoids an extra sync), threads push
// their own candidates, block 0 does the tiny O(m^2) select + combine.
//
// ws layout (4B words):
//   [0,4096)        hist1 (u32)        } zeroed in-kernel
//   [4096,8192)     hist2 (u32)        }
//   [8192,12288)    T1 (f32, Sum(1-2a) per bin)  }
//   [12288,16384)   T2                            }
//   [16384,16386)   cnt1, cnt2 (u32)   }
//   [16400,16656)   partial P1/P2/A21/A22 (4 x 64)
//   [16656,20752)   cand1_u, cand1_a, cand2_u, cand2_a (4 x 1024)

#define N1 12800
#define N2 25600
#define NTOT 38400
#define K1 6399
#define K2 12799
#define NBINS 4096
#define HSHIFT 20
#define CAP 1024
#define NB 38   // ceil(38400/1024)

__device__ __forceinline__ unsigned fkey(float f) {
    unsigned u = __float_as_uint(f);
    return (u & 0x80000000u) ? ~u : (u | 0x80000000u);
}

// blockDim == 1024 (16 waves). Valid at t==0.
__device__ __forceinline__ float block_reduce(float v, float* red) {
    const int lane = threadIdx.x & 63;
    const int wid  = threadIdx.x >> 6;
#pragma unroll
    for (int o = 32; o > 0; o >>= 1) v += __shfl_down(v, o, 64);
    if (lane == 0) red[wid] = v;
    __syncthreads();
    if (wid == 0) {
        v = (lane < 16) ? red[lane] : 0.f;
#pragma unroll
        for (int o = 8; o > 0; o >>= 1) v += __shfl_down(v, o, 64);
    }
    __syncthreads();
    return v;
}

// Find bin containing rank k + residual rank. All 1024 threads enter.
__device__ void hist_scan(const unsigned* __restrict__ histg, int k,
                          unsigned* sh_h, unsigned* sh_csum, unsigned* sh_wsum,
                          int* sh_bin, int* sh_kk)
{
    const int t = threadIdx.x;
    __syncthreads();
    for (int i = t; i < NBINS; i += 1024) sh_h[i] = histg[i];
    __syncthreads();
    unsigned c = sh_h[4*t] + sh_h[4*t+1] + sh_h[4*t+2] + sh_h[4*t+3];
    sh_csum[t] = c;
    unsigned wv = c;
#pragma unroll
    for (int o = 32; o > 0; o >>= 1) wv += __shfl_down(wv, o, 64);
    if ((t & 63) == 0) sh_wsum[t >> 6] = wv;
    __syncthreads();
    if (t == 0) {
        int rem = k;
        int w = 0;
        for (; w < 16; ++w) { unsigned s = sh_wsum[w]; if ((unsigned)rem < s) break; rem -= (int)s; }
        int tc = w * 64;
        for (; tc < (w + 1) * 64; ++tc) { unsigned s = sh_csum[tc]; if ((unsigned)rem < s) break; rem -= (int)s; }
        int b = tc * 4;
        for (; b < tc * 4 + 4; ++b) { unsigned s = sh_h[b]; if ((unsigned)rem < s) break; rem -= (int)s; }
        *sh_bin = b;
        *sh_kk  = rem;
    }
    __syncthreads();
}

// Exact-rank select over m candidates + boundary correction Sum_{u>=um}(1-2a).
// Valid at t==0. Block 0 only.
__device__ float cand_corr(const unsigned* __restrict__ gu, const float* __restrict__ ga,
                           int m, int kk,
                           unsigned* cu, float* ca, unsigned* sh_res, float* red)
{
    const int t = threadIdx.x;
    for (int i = t; i < m; i += 1024) { cu[i] = gu[i]; ca[i] = ga[i]; }
    __syncthreads();
    for (int i = t; i < m; i += 1024) {
        unsigned ui = cu[i];
        int r = 0;
        for (int j = 0; j < m; ++j) { unsigned uj = cu[j]; r += (uj < ui) || (uj == ui && j < i); }
        if (r == kk) *sh_res = ui;   // exactly one writer
    }
    __syncthreads();
    const unsigned um = *sh_res;
    float cc = 0.f;
    for (int i = t; i < m; i += 1024)
        if (cu[i] >= um) cc += 1.f - 2.f * ca[i];
    return block_reduce(cc, red);
}

__global__ __launch_bounds__(1024) void fused_kernel(
    const float* __restrict__ c2, const float* __restrict__ c3,
    const float* __restrict__ vm1, const float* __restrict__ vm2,
    const float* __restrict__ am1, const float* __restrict__ am2,
    float* __restrict__ ws, float* __restrict__ out)
{
    unsigned* hist1 = (unsigned*)ws;
    unsigned* hist2 = hist1 + NBINS;
    float* T1 = ws + 2*NBINS;
    float* T2 = T1 + NBINS;
    unsigned* cnts = (unsigned*)(T2 + NBINS);      // 2 words @16384
    float* pP1 = ws + 16400;
    float* pP2 = pP1 + 64;
    float* pA1 = pP2 + 64;
    float* pA2 = pA1 + 64;
    unsigned* c1u = (unsigned*)(pA2 + 64);         // @16656
    float*    c1a = (float*)(c1u + CAP);
    unsigned* c2u = (unsigned*)(c1a + CAP);
    float*    c2a = (float*)(c2u + CAP);

    __shared__ unsigned sh_h[NBINS];
    __shared__ unsigned sh_csum[1024];
    __shared__ unsigned sh_wsum[16];
    __shared__ unsigned sh_cu[CAP];
    __shared__ float    sh_ca[CAP];
    __shared__ float    red[16];
    __shared__ int sh_bin, sh_kk;
    __shared__ unsigned sh_res;

    cg::grid_group grid = cg::this_grid();
    const int t = threadIdx.x;
    const int g = blockIdx.x * 1024 + t;
    const bool act1 = (g < N1);
    const bool act2 = (g >= N1) && (g < NTOT);

    // Issue gathered loads early; they complete under the first grid sync.
    float v = 0.f, a = 0.f, d = 0.f;
    if (act1) {
        v = c2[(size_t)g * 3136 + 399];            // 7*56+7
        a = am1[g];
        d = v - vm1[g];
    } else if (act2) {
        int j = g - N1;
        v = c3[(size_t)j * 784 + 87];              // 3*28+3
        a = am2[j];
        d = v - vm2[j];
    }

    // Zero hist1,hist2 (u32), T1,T2 (f32), counters — 16386 words, 38912 threads.
    if (g < 2*NBINS) ((unsigned*)ws)[g] = 0u;
    else if (g < 4*NBINS) ws[g] = 0.f;
    else if (g < 4*NBINS + 2) cnts[g - 4*NBINS] = 0u;
    grid.sync();

    // Histogram + T accumulation + per-block partial sums.
    const unsigned key = fkey(v);
    const unsigned b = key >> HSHIFT;
    if (act1) { atomicAdd(&hist1[b], 1u); atomicAdd(&T1[b], 1.f - 2.f * a); }
    else if (act2) { atomicAdd(&hist2[b], 1u); atomicAdd(&T2[b], 1.f - 2.f * a); }
    float r;
    r = block_reduce(act1 ? d * d : 0.f, red);  if (t == 0) pP1[blockIdx.x] = r;
    r = block_reduce(act2 ? d * d : 0.f, red);  if (t == 0) pP2[blockIdx.x] = r;
    r = block_reduce(act1 ? a * a : 0.f, red);  if (t == 0) pA1[blockIdx.x] = r;
    r = block_reduce(act2 ? a * a : 0.f, red);  if (t == 0) pA2[blockIdx.x] = r;
    grid.sync();

    // Every block redundantly finds both median bins from the global hists
    // (16KB L2-resident reads; avoids an extra broadcast grid sync).
    hist_scan(hist1, K1, sh_h, sh_csum, sh_wsum, &sh_bin, &sh_kk);
    const int b1 = sh_bin, kk1 = sh_kk;
    hist_scan(hist2, K2, sh_h, sh_csum, sh_wsum, &sh_bin, &sh_kk);
    const int b2 = sh_bin, kk2 = sh_kk;

    // Suffix sums over T (bins strictly above the median bin): block 0 only.
    float suff1 = 0.f, suff2 = 0.f;
    if (blockIdx.x == 0) {
        float sv = 0.f;
#pragma unroll
        for (int j = 0; j < 4; ++j) { int bb = 4*t + j; if (bb > b1) sv += T1[bb]; }
        suff1 = block_reduce(sv, red);
        sv = 0.f;
#pragma unroll
        for (int j = 0; j < 4; ++j) { int bb = 4*t + j; if (bb > b2) sv += T2[bb]; }
        suff2 = block_reduce(sv, red);
    }

    // Candidate push straight from registers — no W arrays, no O(N) rescan.
    if (act1 && (int)b == b1) {
        unsigned p = atomicAdd(&cnts[0], 1u);
        if (p < CAP) { c1u[p] = key; c1a[p] = a; }
    }
    if (act2 && (int)b == b2) {
        unsigned p = atomicAdd(&cnts[1], 1u);
        if (p < CAP) { c2u[p] = key; c2a[p] = a; }
    }
    grid.sync();

    if (blockIdx.x != 0) return;

    // Final combine in block 0.
    float s1  = block_reduce((t < NB) ? pP1[t] : 0.f, red);
    float s2  = block_reduce((t < NB) ? pP2[t] : 0.f, red);
    float a21 = block_reduce((t < NB) ? pA1[t] : 0.f, red);
    float a22 = block_reduce((t < NB) ? pA2[t] : 0.f, red);

    int m1 = (cnts[0] < (unsigned)CAP) ? (int)cnts[0] : CAP;
    int m2 = (cnts[1] < (unsigned)CAP) ? (int)cnts[1] : CAP;
    float corr1 = cand_corr(c1u, c1a, m1, kk1, sh_cu, sh_ca, &sh_res, red);
    float corr2 = cand_corr(c2u, c2a, m2, kk2, sh_cu, sh_ca, &sh_res, red);

    if (t == 0) {
        float q1 = a21 + suff1 + corr1;
        float q2 = a22 + suff2 + corr2;
        out[0] = (sqrtf(s1) + sqrtf(s2)) / 38400.f;
        out[1] = (sqrtf(q1) + sqrtf(q2)) / 384.f;
    }
}

extern "C" void kernel_launch(void* const* d_in, const int* in_sizes, int n_in,
                              void* d_out, int out_size, void* d_ws, size_t ws_size,
                              hipStream_t stream) {
    const float* c2  = (const float*)d_in[0];
    const float* c3  = (const float*)d_in[1];
    const float* vm1 = (const float*)d_in[2];
    const float* vm2 = (const float*)d_in[3];
    const float* am1 = (const float*)d_in[4];
    const float* am2 = (const float*)d_in[5];
    float* ws  = (float*)d_ws;
    float* out = (float*)d_out;

    void* args[] = { &c2, &c3, &vm1, &vm2, &am1, &am2, &ws, &out };
    hipLaunchCooperativeKernel((void*)fused_kernel, dim3(NB), dim3(1024),
                               args, 0, stream);
}

// Round 2
// 258.195 us; speedup vs baseline: 1.1930x; 1.1930x over previous
//
#include <hip/hip_runtime.h>
#include <math.h>

// p = (||c2[:,:,7,7]-vmask1|| + ||c3[:,:,3,3]-vmask2||) / 38400
// m = exact lower median (k-th smallest, k=(n-1)/2) of each gathered slice
// q = (||(tm1<m?0:1)-amask|| ...) / 384,  q-sum = Sum(a^2) + Sum_{v>=m}(1-2a)
//
// R5: two plain dispatches (R4's cooperative launch cost +24us — reverted).
//  - gather (150x256): writes monotone sort-keys W1/W2 + per-block P partials.
//    No histogram atomics, no T arrays, no am reads -> no memset dispatch.
//  - finish (1x1024): LDS histogram built from keys held in REGISTERS
//    (13/25 per thread, static-unrolled), bin scan, then one register pass
//    computes Sum(a^2) + suffix(1-2a) + collects median-bin candidates;
//    O(m^2) exact-rank select (m ~ 6) + boundary correction.
//
// ws layout (4B words): [0,12800) W1 keys | [12800,38400) W2 keys
//                       [38400,38560) partialP (150)

#define N1 12800
#define N2 25600
#define K1 6399
#define K2 12799
#define NBINS 4096
#define HSHIFT 20
#define CAP 1024
#define J1 13   // ceil(N1/1024)
#define J2 25   // ceil(N2/1024)

__device__ __forceinline__ unsigned fkey(float f) {
    unsigned u = __float_as_uint(f);
    return (u & 0x80000000u) ? ~u : (u | 0x80000000u);
}

// blockDim == 256 (4 waves). Valid at t==0.
__device__ __forceinline__ float block_reduce256(float v, float* red) {
    const int lane = threadIdx.x & 63;
    const int wid  = threadIdx.x >> 6;
#pragma unroll
    for (int o = 32; o > 0; o >>= 1) v += __shfl_down(v, o, 64);
    if (lane == 0) red[wid] = v;
    __syncthreads();
    if (wid == 0) {
        v = (lane < 4) ? red[lane] : 0.f;
        v += __shfl_down(v, 2, 64);
        v += __shfl_down(v, 1, 64);
    }
    __syncthreads();
    return v;
}

// blockDim == 1024 (16 waves). Valid at t==0.
__device__ __forceinline__ float block_reduce1024(float v, float* red) {
    const int lane = threadIdx.x & 63;
    const int wid  = threadIdx.x >> 6;
#pragma unroll
    for (int o = 32; o > 0; o >>= 1) v += __shfl_down(v, o, 64);
    if (lane == 0) red[wid] = v;
    __syncthreads();
    if (wid == 0) {
        v = (lane < 16) ? red[lane] : 0.f;
#pragma unroll
        for (int o = 8; o > 0; o >>= 1) v += __shfl_down(v, o, 64);
    }
    __syncthreads();
    return v;
}

// 150 blocks x 256. Blocks [0,50): tm1; [50,150): tm2.
__global__ __launch_bounds__(256) void gather_kernel(
    const float* __restrict__ c2, const float* __restrict__ c3,
    const float* __restrict__ vm1, const float* __restrict__ vm2,
    unsigned* __restrict__ W1, unsigned* __restrict__ W2,
    float* __restrict__ partialP)
{
    __shared__ float red[4];
    const int g = blockIdx.x * 256 + threadIdx.x;
    float d;
    if (g < N1) {
        float v = c2[(size_t)g * 3136 + 399];   // 7*56+7
        W1[g] = fkey(v);
        d = v - vm1[g];
    } else {
        int j = g - N1;
        float v = c3[(size_t)j * 784 + 87];     // 3*28+3
        W2[j] = fkey(v);
        d = v - vm2[j];
    }
    float pss = block_reduce256(d * d, red);
    if (threadIdx.x == 0) partialP[blockIdx.x] = pss;
}

// One array's q-sum: Sum(a^2) + Sum_{v>=median}(1-2a). Valid at t==0.
// Keys held in registers across hist-build -> scan -> accumulate pass.
template<int J, int N>
__device__ float process(const unsigned* __restrict__ Wk,
                         const float* __restrict__ am, int K,
                         unsigned* sh_h, unsigned* sh_csum, unsigned* sh_wsum,
                         unsigned* sh_cu, float* sh_ca, float* red,
                         int* sh_bin, int* sh_kk, int* sh_m, unsigned* sh_res)
{
    const int t = threadIdx.x;

    // zero LDS hist + candidate counter (leading sync protects prior phase)
    __syncthreads();
    for (int i = t; i < NBINS; i += 1024) sh_h[i] = 0u;
    if (t == 0) *sh_m = 0;
    __syncthreads();

    // pass 1: load own keys into registers, build LDS histogram
    unsigned k[J];
#pragma unroll
    for (int j = 0; j < J; ++j) {
        int i = t + j * 1024;
        if (i < N) {
            unsigned u = Wk[i];
            k[j] = u;
            atomicAdd(&sh_h[u >> HSHIFT], 1u);
        } else {
            k[j] = 0u;
        }
    }
    __syncthreads();

    // scan: find bin containing rank K + residual rank
    unsigned c = sh_h[4*t] + sh_h[4*t+1] + sh_h[4*t+2] + sh_h[4*t+3];
    sh_csum[t] = c;
    unsigned wv = c;
#pragma unroll
    for (int o = 32; o > 0; o >>= 1) wv += __shfl_down(wv, o, 64);
    if ((t & 63) == 0) sh_wsum[t >> 6] = wv;
    __syncthreads();
    if (t == 0) {
        int rem = K;
        int w = 0;
        for (; w < 16; ++w) { unsigned s = sh_wsum[w]; if ((unsigned)rem < s) break; rem -= (int)s; }
        int tc = w * 64;
        for (; tc < (w + 1) * 64; ++tc) { unsigned s = sh_csum[tc]; if ((unsigned)rem < s) break; rem -= (int)s; }
        int b = tc * 4;
        for (; b < tc * 4 + 4; ++b) { unsigned s = sh_h[b]; if ((unsigned)rem < s) break; rem -= (int)s; }
        *sh_bin = b;
        *sh_kk  = rem;
    }
    __syncthreads();
    const int bm = *sh_bin, kk = *sh_kk;

    // pass 2 (registers + coalesced am read): a^2 + suffix(1-2a) + candidates
    float cc = 0.f;
#pragma unroll
    for (int j = 0; j < J; ++j) {
        int i = t + j * 1024;
        if (i < N) {
            float a = am[i];
            cc += a * a;
            unsigned u = k[j];
            int bb = (int)(u >> HSHIFT);
            if (bb > bm) {
                cc += 1.f - 2.f * a;
            } else if (bb == bm) {
                int p = atomicAdd(sh_m, 1);
                if (p < CAP) { sh_cu[p] = u; sh_ca[p] = a; }
            }
        }
    }
    __syncthreads();
    const int m = (*sh_m < CAP) ? *sh_m : CAP;

    // exact-rank select among candidates (index tiebreak -> unique writer)
    for (int i = t; i < m; i += 1024) {
        unsigned ui = sh_cu[i];
        int r = 0;
        for (int j = 0; j < m; ++j) {
            unsigned uj = sh_cu[j];
            r += (uj < ui) || (uj == ui && j < i);
        }
        if (r == kk) *sh_res = ui;
    }
    __syncthreads();
    const unsigned um = *sh_res;
    for (int i = t; i < m; i += 1024)
        if (sh_cu[i] >= um) cc += 1.f - 2.f * sh_ca[i];

    return block_reduce1024(cc, red);
}

__global__ __launch_bounds__(1024) void finish_kernel(
    const unsigned* __restrict__ W1, const unsigned* __restrict__ W2,
    const float* __restrict__ partialP,
    const float* __restrict__ am1, const float* __restrict__ am2,
    float* __restrict__ out)
{
    __shared__ unsigned sh_h[NBINS];
    __shared__ unsigned sh_csum[1024];
    __shared__ unsigned sh_wsum[16];
    __shared__ unsigned sh_cu[CAP];
    __shared__ float    sh_ca[CAP];
    __shared__ float    red[16];
    __shared__ int sh_bin, sh_kk, sh_m;
    __shared__ unsigned sh_res;

    const int t = threadIdx.x;

    // p partials (same reduction order as R3's bit-exact path)
    float s1 = block_reduce1024((t < 50) ? partialP[t] : 0.f, red);
    float s2 = block_reduce1024((t >= 50 && t < 150) ? partialP[t] : 0.f, red);

    float q1 = process<J1, N1>(W1, am1, K1, sh_h, sh_csum, sh_wsum,
                               sh_cu, sh_ca, red, &sh_bin, &sh_kk, &sh_m, &sh_res);
    float q2 = process<J2, N2>(W2, am2, K2, sh_h, sh_csum, sh_wsum,
                               sh_cu, sh_ca, red, &sh_bin, &sh_kk, &sh_m, &sh_res);

    if (t == 0) {
        out[0] = (sqrtf(s1) + sqrtf(s2)) / 38400.f;
        out[1] = (sqrtf(q1) + sqrtf(q2)) / 384.f;
    }
}

extern "C" void kernel_launch(void* const* d_in, const int* in_sizes, int n_in,
                              void* d_out, int out_size, void* d_ws, size_t ws_size,
                              hipStream_t stream) {
    const float* c2  = (const float*)d_in[0];
    const float* c3  = (const float*)d_in[1];
    const float* vm1 = (const float*)d_in[2];
    const float* vm2 = (const float*)d_in[3];
    const float* am1 = (const float*)d_in[4];
    const float* am2 = (const float*)d_in[5];
    float* out = (float*)d_out;

    float* ws = (float*)d_ws;
    unsigned* W1       = (unsigned*)ws;            // 12800
    unsigned* W2       = W1 + N1;                  // 25600
    float*    partialP = ws + 38400;               // 150

    gather_kernel<<<150, 256, 0, stream>>>(c2, c3, vm1, vm2, W1, W2, partialP);
    finish_kernel<<<1, 1024, 0, stream>>>(W1, W2, partialP, am1, am2, out);
}